// Round 11
// baseline (171.078 us; speedup 1.0000x reference)
//
#include <hip/hip_runtime.h>

// DenseFeatureNumericEmbedding: out[b, f*16+e] = sum_h relu(x[b,f]*W1[f,h]+b1[f,h])*W2[f,e,h] + b2[f,e]
// Piecewise-linear reformulation: per (f,e) the map x->emb is piecewise linear with
// breakpoints t_h = -b1/W1; tables hold slope/intercept per (f, interval, e).
//
// Ledger: R5a build (f,e)-parallel [-28us CONFIRMED]; R5b LDS->L2 reads [neutral];
// R8 grid swap [neutral]; R9 nt->plain store [neutral]. Decomposition (proven by
// top-5 bounds + BW floor): timed window = ~83us harness fill + ~4us build + ~78us
// embed. Embed writes 134MB at only 1.7TB/s effective vs the fill's 6.4TB/s.
// R10 (structural test): make embed's write stream FILL-LIKE.
//   block = 16 consecutive rows x ALL 128 features; thread owns features tid>>2 and
//   tid>>2+64, e-quartet tid&3 -> per row two stores at row+tid*16B / +4096+tid*16B:
//   every wave-store is ONE dense 1KB segment, each block sweeps 128KB sequentially
//   (vs 4x256B fragments on 8KB-strided rows before). Digitize: bp quartered across
//   the 4 el-lanes (16 cmps/feature + 2 shfl_xor). x loads single-line per instr.
// R11/R12: identical resubmits (GPU acquisition timeouts; R10 never measured).

#define F_   128
#define H_   64
#define E_   16
#define NROW 65            // intervals 0..64
#define GRS  32            // table row stride in floats (16 S + 16 T)
#define RPB  16            // batch rows per block
#define THREADS 256

typedef float vf4 __attribute__((ext_vector_type(4)));

// ---------------- build kernel: one wave per (feature, e) ----------------
__global__ __launch_bounds__(64) void build_tables(
    const float* __restrict__ W1, const float* __restrict__ B1,
    const float* __restrict__ W2, const float* __restrict__ B2,
    float* __restrict__ tbl, float* __restrict__ bps)
{
    const int f = blockIdx.x;   // 0..127
    const int e = blockIdx.y;   // 0..15
    const int h = threadIdx.x;  // 0..63

    __shared__ float ts_raw[H_];
    __shared__ float ts_sorted[H_];
    __shared__ float scS[H_];
    __shared__ float scT[H_];

    const float w1 = W1[f * H_ + h];
    const float bb = B1[f * H_ + h];
    const bool  slope = (w1 != 0.0f);
    const float t   = slope ? (-bb / w1) : __builtin_inff();
    const float sgn = slope ? (w1 > 0.0f ? 1.0f : -1.0f) : 0.0f;
    // active as x -> -inf: W1<0 terms (x*W1 -> +inf), plus constant-on terms (W1==0, b1>0)
    const bool act0 = (w1 < 0.0f) || (!slope && bb > 0.0f);

    ts_raw[h] = t;
    __syncthreads();
    int rank = 0;
    #pragma unroll
    for (int j = 0; j < H_; ++j) {
        float tj = ts_raw[j];
        rank += (tj < t || (tj == t && j < h)) ? 1 : 0;  // tie-break by index -> permutation
    }
    ts_sorted[rank] = t;
    __syncthreads();
    if (e == 0) bps[f * H_ + h] = ts_sorted[h];

    const float w2 = W2[(f * E_ + e) * H_ + h];
    // crossing t_h upward: W1>0 -> term turns ON (+), W1<0 -> OFF (-)
    const float dS = sgn * w1 * w2;
    const float dT = sgn * bb * w2;
    float bS = act0 ? w1 * w2 : 0.0f;
    float bT = act0 ? bb * w2 : 0.0f;
    #pragma unroll
    for (int d = 32; d; d >>= 1) { bS += __shfl_xor(bS, d); bT += __shfl_xor(bT, d); }

    scS[rank] = dS; scT[rank] = dT;  // scatter deltas into sorted order
    __syncthreads();
    float vS = scS[h], vT = scT[h];
    #pragma unroll
    for (int d = 1; d < 64; d <<= 1) {   // inclusive scan over sorted positions
        float uS = __shfl_up(vS, (unsigned)d);
        float uT = __shfl_up(vT, (unsigned)d);
        if (h >= d) { vS += uS; vT += uT; }
    }
    const float b2v = B2[f * E_ + e];
    float* row = tbl + ((size_t)f * NROW + (h + 1)) * GRS;  // interval k = h+1
    row[e]      = bS + vS;
    row[E_ + e] = bT + vT + b2v;
    if (h == 0) {
        float* r0 = tbl + (size_t)f * NROW * GRS;           // interval 0
        r0[e]      = bS;
        r0[E_ + e] = bT + b2v;
    }
}

// ---------------- main kernel: fill-like dense stores ----------------
// el = tid&3 (e-quartet), fq = tid>>2 (0..63): thread owns features fq and fq+64.
// Output bytes per row: A at tid*16, B at 4096 + tid*16 -> each wave-store is one
// dense 1KB segment; a block writes 16 consecutive 8KB rows = 128KB sequential.
__global__ __launch_bounds__(THREADS, 4) void embed_main(
    const float* __restrict__ x, const float* __restrict__ tbl,
    const float* __restrict__ bps, float* __restrict__ out)
{
    const int tid = threadIdx.x;
    const int el  = tid & 3;
    const int fq  = tid >> 2;
    const int fA  = fq;
    const int fB  = fq + 64;
    const int r0  = blockIdx.x * RPB;

    // x values for both features, all rows (independent gathers, issued upfront)
    float xsA[RPB], xsB[RPB];
    #pragma unroll
    for (int i = 0; i < RPB; ++i) {
        xsA[i] = x[(size_t)(r0 + i) * F_ + fA];
        xsB[i] = x[(size_t)(r0 + i) * F_ + fB];
    }

    // this lane's quarter (16) of each feature's 64 sorted breakpoints
    float4 bpA[4], bpB[4];
    #pragma unroll
    for (int i = 0; i < 4; ++i) {
        bpA[i] = *(const float4*)(bps + (size_t)fA * H_ + el * 16 + 4 * i);
        bpB[i] = *(const float4*)(bps + (size_t)fB * H_ + el * 16 + 4 * i);
    }

    const float* tA = tbl + (size_t)fA * NROW * GRS;
    const float* tB = tbl + (size_t)fB * NROW * GRS;

    #pragma unroll
    for (int i = 0; i < RPB; ++i) {
        const float xa = xsA[i];
        const float xb = xsB[i];
        // quarter-counts of breakpoints <= x (order-independent), pure VALU
        int ca = 0, cb = 0;
        #pragma unroll
        for (int j = 0; j < 4; ++j) {
            ca += (bpA[j].x <= xa) ? 1 : 0;
            ca += (bpA[j].y <= xa) ? 1 : 0;
            ca += (bpA[j].z <= xa) ? 1 : 0;
            ca += (bpA[j].w <= xa) ? 1 : 0;
            cb += (bpB[j].x <= xb) ? 1 : 0;
            cb += (bpB[j].y <= xb) ? 1 : 0;
            cb += (bpB[j].z <= xb) ? 1 : 0;
            cb += (bpB[j].w <= xb) ? 1 : 0;
        }
        // combine across the 4 el-lanes (lane bits 0-1; they share f and x)
        ca += __shfl_xor(ca, 1);  cb += __shfl_xor(cb, 1);
        ca += __shfl_xor(ca, 2);  cb += __shfl_xor(cb, 2);

        // table rows (L2-resident; el-lanes read dense 64B per feature)
        const float* rowA = tA + (size_t)ca * GRS + el * 4;
        const float* rowB = tB + (size_t)cb * GRS + el * 4;
        float4 SA = *(const float4*)(rowA);
        float4 TA = *(const float4*)(rowA + E_);
        float4 SB = *(const float4*)(rowB);
        float4 TB = *(const float4*)(rowB + E_);

        vf4 oA, oB;
        oA.x = fmaf(SA.x, xa, TA.x);
        oA.y = fmaf(SA.y, xa, TA.y);
        oA.z = fmaf(SA.z, xa, TA.z);
        oA.w = fmaf(SA.w, xa, TA.w);
        oB.x = fmaf(SB.x, xb, TB.x);
        oB.y = fmaf(SB.y, xb, TB.y);
        oB.z = fmaf(SB.z, xb, TB.z);
        oB.w = fmaf(SB.w, xb, TB.w);

        float* orow = out + (size_t)(r0 + i) * (F_ * E_);
        *(vf4*)(orow + tid * 4)            = oA;   // bytes [tid*16, +16) of row
        *(vf4*)(orow + 1024 + tid * 4)     = oB;   // bytes [4096 + tid*16, +16)
    }
}

extern "C" void kernel_launch(void* const* d_in, const int* in_sizes, int n_in,
                              void* d_out, int out_size, void* d_ws, size_t ws_size,
                              hipStream_t stream) {
    const float* x  = (const float*)d_in[0];
    const float* W1 = (const float*)d_in[1];
    const float* b1 = (const float*)d_in[2];
    const float* W2 = (const float*)d_in[3];
    const float* b2 = (const float*)d_in[4];
    float* out = (float*)d_out;
    const int B = in_sizes[0] / F_;     // 16384

    // workspace: table 128*65*32 floats (1.02 MB) + sorted breakpoints 128*64 floats (32 KB)
    float* tbl = (float*)d_ws;
    float* bps = tbl + (size_t)F_ * NROW * GRS;

    build_tables<<<dim3(F_, E_), 64, 0, stream>>>(W1, b1, W2, b2, tbl, bps);
    embed_main<<<B / RPB, THREADS, 0, stream>>>(x, tbl, bps, out);  // 1024 blocks, 4/CU
}